// Round 8
// baseline (1782.734 us; speedup 1.0000x reference)
//
#include <hip/hip_runtime.h>
#include <hip/hip_bf16.h>
#include <math.h>

#define T_STEPS 256
#define BATCH   128
#define IN_DIM  1024
#define LAT     2048

// recurrence decomposition
#define NG      8     // independent batch-row groups (16 rows each)
#define GB      32    // blocks per group (64 cols each)
#define GROWS   16
#define GCOLS   64

typedef __bf16 bf16x8 __attribute__((ext_vector_type(8)));
typedef __bf16 bf16x4 __attribute__((ext_vector_type(4)));
typedef float  f32x4  __attribute__((ext_vector_type(4)));
typedef float  f32x2  __attribute__((ext_vector_type(2)));

#define MFMA16 __builtin_amdgcn_mfma_f32_16x16x32_bf16

// ---------------------------------------------------------------------------
// Coherent (agent-scope, L1/L2-bypassing, MALL-served) accessors for the
// cross-block h plane.
// ---------------------------------------------------------------------------
__device__ __forceinline__ void coh_store32(__bf16* p, unsigned int v) {
    __hip_atomic_store((unsigned int*)p, v,
                       __ATOMIC_RELAXED, __HIP_MEMORY_SCOPE_AGENT);
}
__device__ __forceinline__ unsigned int pack_bf16(float a, float b) {
    union { __bf16 h[2]; unsigned int u; } p;
    p.h[0] = (__bf16)a; p.h[1] = (__bf16)b;
    return p.u;
}

// ---------------------------------------------------------------------------
// LDS tile helpers for k_xproj (unchanged).
// ---------------------------------------------------------------------------
__device__ __forceinline__ int swz(int row, int kbyte) {
    return (row * 64 + kbyte) ^ ((row & 7) << 4);
}

template<int ROWS>
__device__ __forceinline__ void stage_load(const float* __restrict__ src, int ld,
                                           int tid, f32x4* regs) {
#pragma unroll
    for (int rnd = 0; rnd < ROWS / 32; ++rnd) {
        int r  = rnd * 32 + (tid >> 3);
        int kc = (tid & 7) * 4;
        regs[rnd] = *(const f32x4*)(src + (size_t)r * ld + kc);
    }
}

template<int ROWS>
__device__ __forceinline__ void stage_write(const f32x4* regs, char* hi, char* lo,
                                            int tid) {
#pragma unroll
    for (int rnd = 0; rnd < ROWS / 32; ++rnd) {
        int r  = rnd * 32 + (tid >> 3);
        int kc = (tid & 7) * 4;
        bf16x4 vh, vl;
        f32x4  v = regs[rnd];
#pragma unroll
        for (int e = 0; e < 4; ++e) {
            float x = v[e];
            __bf16 h = (__bf16)x;
            vh[e] = h;
            vl[e] = (__bf16)(x - (float)h);
        }
        int off = swz(r, kc * 2);
        *(bf16x4*)(hi + off) = vh;
        *(bf16x4*)(lo + off) = vl;
    }
}

__device__ __forceinline__ bf16x8 ld_frag(const char* p, int row, int kb) {
    return *(const bf16x8*)(p + swz(row, kb));
}

__device__ __forceinline__ void split8(f32x4 v0, f32x4 v1, bf16x8& hi, bf16x8& lo) {
#pragma unroll
    for (int e = 0; e < 4; ++e) {
        __bf16 h0 = (__bf16)v0[e];
        hi[e]     = h0;
        lo[e]     = (__bf16)(v0[e] - (float)h0);
        __bf16 h1 = (__bf16)v1[e];
        hi[e + 4] = h1;
        lo[e + 4] = (__bf16)(v1[e] - (float)h1);
    }
}

// ---------------------------------------------------------------------------
// Prep: Wh (fp32) -> hi bf16 plane.
// ---------------------------------------------------------------------------
__global__ __launch_bounds__(256)
void k_prep(const float* __restrict__ W, __bf16* __restrict__ hi)
{
    size_t i = ((size_t)blockIdx.x * 256 + threadIdx.x) * 4;
    f32x4 v = *(const f32x4*)(W + i);
    bf16x4 vh;
#pragma unroll
    for (int e = 0; e < 4; ++e) vh[e] = (__bf16)v[e];
    *(bf16x4*)(hi + i) = vh;
}

// ---------------------------------------------------------------------------
// Phase 1: xi = x @ W_i^T + b_i -> out (fp32); t==0 rows get tanh and seed
// the h ping buffer (bf16-hi).
// ---------------------------------------------------------------------------
__global__ __launch_bounds__(256, 2)
void k_xproj(const float* __restrict__ x, const float* __restrict__ Wi,
             const float* __restrict__ bi, float* __restrict__ out,
             __bf16* __restrict__ h0hi)
{
    __shared__ __align__(16) char lds[32 * 1024];
    char* Ahi = lds;
    char* Alo = lds + 8192;
    char* Bhi = lds + 16384;
    char* Blo = lds + 24576;

    int tid  = threadIdx.x;
    int lane = tid & 63;
    int w    = tid >> 6;
    int wm   = (w >> 1) * 64;
    int wn   = (w & 1) * 64;
    int bm   = blockIdx.y * 128;
    int bn   = blockIdx.x * 128;

    const float* Abase = x  + (size_t)bm * IN_DIM;
    const float* Bbase = Wi + (size_t)bn * IN_DIM;

    f32x4 acc[4][4] = {};
    f32x4 ra[4], rb[4];

    stage_load<128>(Abase, IN_DIM, tid, ra);
    stage_load<128>(Bbase, IN_DIM, tid, rb);

    for (int k0 = 0; k0 < IN_DIM; k0 += 32) {
        stage_write<128>(ra, Ahi, Alo, tid);
        stage_write<128>(rb, Bhi, Blo, tid);
        __syncthreads();

        if (k0 + 32 < IN_DIM) {
            stage_load<128>(Abase + k0 + 32, IN_DIM, tid, ra);
            stage_load<128>(Bbase + k0 + 32, IN_DIM, tid, rb);
        }

        int kb = (lane >> 4) * 16;
        bf16x8 ah[4], al[4], bh[4], bl[4];
#pragma unroll
        for (int i = 0; i < 4; ++i) {
            int rrow = i * 16 + (lane & 15);
            ah[i] = ld_frag(Ahi, wm + rrow, kb);
            al[i] = ld_frag(Alo, wm + rrow, kb);
            bh[i] = ld_frag(Bhi, wn + rrow, kb);
            bl[i] = ld_frag(Blo, wn + rrow, kb);
        }
#pragma unroll
        for (int i = 0; i < 4; ++i)
#pragma unroll
            for (int j = 0; j < 4; ++j) {
                acc[i][j] = MFMA16(ah[i], bh[j], acc[i][j], 0, 0, 0);
                acc[i][j] = MFMA16(ah[i], bl[j], acc[i][j], 0, 0, 0);
                acc[i][j] = MFMA16(al[i], bh[j], acc[i][j], 0, 0, 0);
            }
        __syncthreads();
    }

#pragma unroll
    for (int j = 0; j < 4; ++j) {
        int n = bn + wn + j * 16 + (lane & 15);
        float bias = bi[n];
#pragma unroll
        for (int i = 0; i < 4; ++i) {
            int m0 = bm + wm + i * 16 + ((lane >> 4) * 4);
#pragma unroll
            for (int r = 0; r < 4; ++r) {
                float v = acc[i][j][r] + bias;
                if (m0 + r < BATCH) {
                    v = tanhf(v);                       // t == 0: h0 = tanh(xi)
                    if (h0hi)
                        h0hi[(size_t)(m0 + r) * LAT + n] = (__bf16)v;
                }
                out[(size_t)(m0 + r) * LAT + n] = v;
            }
        }
    }
}

// coherent 16-B load, agent scope (sc1): bypasses L1/L2, served by MALL
#define LOADA(dst, off)                                                       \
    asm volatile("global_load_dwordx4 %0, %1, off offset:" #off " sc1"        \
                 : "=v"(dst) : "v"(Ar) : "memory")

// plain 16-B load via asm: OPAQUE to the compiler -> result cannot be
// rematerialized by re-loading in the loop; forces true register parking.
#define LOADB(dst, base, off)                                                 \
    asm volatile("global_load_dwordx4 %0, %1, off offset:" #off               \
                 : "=v"(dst) : "v"(base))

// ---------------------------------------------------------------------------
// Phase 2 (v8): persistent, fence-free, B-stationary (for real this time).
// 256 blocks x 512 threads; 8 groups of 32 blocks barrier independently.
// Block = 16 rows x 64 cols; wave w of 8 owns K-slice [w*256, w*256+256).
// Wh strip (4 col-frags x 8 K-chunks = 128 VGPR) loaded ONCE via inline-asm
// loads -> compiler cannot re-load them in-loop (round 7: VGPR=96 proved the
// C-load + pin version was rematerialized, costing 64 MB/step of L2 reads).
// ---------------------------------------------------------------------------
__global__ __launch_bounds__(512, 2)
void k_recur(const __bf16* __restrict__ Whi,
             __bf16* __restrict__ p0h, __bf16* __restrict__ p1h,
             const float* __restrict__ bias, float* __restrict__ out,
             unsigned int* __restrict__ cnt)
{
    __shared__ __align__(16) float part[8][GROWS][GCOLS + 2];   // pad 64->66

    const int tid  = threadIdx.x;
    const int lane = tid & 63;
    const int w    = tid >> 6;              // wave id == K-slice (0..7)

    const int bid = blockIdx.x;
    const int rg  = bid >> 5;               // row group 0..7
    const int cb  = bid & 31;               // col block 0..31 (XCD = cb%8)
    const int bm  = rg * GROWS;
    const int bn  = cb * GCOLS;

    const int fr    = lane & 15;
    const int kq    = (lane >> 4) * 8;
    const int kbase = w * 256 + kq;

    // --- park this wave's Wh strip in registers via opaque asm loads ---
    bf16x8 bq[4][8];
    {
        const __bf16* B0 = Whi + (size_t)(bn + fr) * LAT + kbase;
        const __bf16* B1 = B0 + (size_t)16 * LAT;
        const __bf16* B2 = B0 + (size_t)32 * LAT;
        const __bf16* B3 = B0 + (size_t)48 * LAT;
        LOADB(bq[0][0], B0,   0); LOADB(bq[0][1], B0,  64);
        LOADB(bq[0][2], B0, 128); LOADB(bq[0][3], B0, 192);
        LOADB(bq[0][4], B0, 256); LOADB(bq[0][5], B0, 320);
        LOADB(bq[0][6], B0, 384); LOADB(bq[0][7], B0, 448);
        LOADB(bq[1][0], B1,   0); LOADB(bq[1][1], B1,  64);
        LOADB(bq[1][2], B1, 128); LOADB(bq[1][3], B1, 192);
        LOADB(bq[1][4], B1, 256); LOADB(bq[1][5], B1, 320);
        LOADB(bq[1][6], B1, 384); LOADB(bq[1][7], B1, 448);
        LOADB(bq[2][0], B2,   0); LOADB(bq[2][1], B2,  64);
        LOADB(bq[2][2], B2, 128); LOADB(bq[2][3], B2, 192);
        LOADB(bq[2][4], B2, 256); LOADB(bq[2][5], B2, 320);
        LOADB(bq[2][6], B2, 384); LOADB(bq[2][7], B2, 448);
        LOADB(bq[3][0], B3,   0); LOADB(bq[3][1], B3,  64);
        LOADB(bq[3][2], B3, 128); LOADB(bq[3][3], B3, 192);
        LOADB(bq[3][4], B3, 256); LOADB(bq[3][5], B3, 320);
        LOADB(bq[3][6], B3, 384); LOADB(bq[3][7], B3, 448);
        asm volatile("s_waitcnt vmcnt(0)" ::: "memory");
        __builtin_amdgcn_sched_barrier(0);
    }

    // combine-phase constants: 512 threads, each owns 2 consecutive cols.
    const int    orow = tid >> 5;                 // 0..15
    const int    oc   = (tid & 31) * 2;           // 0..62
    const size_t idx  = (size_t)(bm + orow) * LAT + bn + oc;
    const float  bv0  = bias[bn + oc];
    const float  bv1  = bias[bn + oc + 1];

    unsigned int* mycnt = cnt + rg * T_STEPS;

    const __bf16* Ah = p0h;                 // read plane (h_{t-1})
    __bf16*       Nh = p1h;                 // write plane (h_t)

    // prologue: xi for t=1
    f32x2 xv = *(const f32x2*)(out + (size_t)1 * (BATCH * LAT) + idx);

    for (int t = 1; t < T_STEPS; ++t) {
        float* io = out + (size_t)t * (BATCH * LAT);
        const __bf16* Ar = Ah + (size_t)(bm + fr) * LAT + kbase;

        bf16x8 a[8];
        LOADA(a[0],   0);
        LOADA(a[1],  64);
        LOADA(a[2], 128);
        LOADA(a[3], 192);
        LOADA(a[4], 256);
        LOADA(a[5], 320);
        LOADA(a[6], 384);
        LOADA(a[7], 448);
        asm volatile("s_waitcnt vmcnt(0)" ::: "memory");
        __builtin_amdgcn_sched_barrier(0);

        f32x4 acc[4] = {};
#pragma unroll
        for (int i = 0; i < 8; ++i)
#pragma unroll
            for (int cf = 0; cf < 4; ++cf)
                acc[cf] = MFMA16(a[i], bq[cf][i], acc[cf], 0, 0, 0);

        // prefetch next step's xi (hidden under reduce + barrier)
        f32x2 xn = {};
        if (t + 1 < T_STEPS)
            xn = *(const f32x2*)(out + (size_t)(t + 1) * (BATCH * LAT) + idx);

        // dump partials. C-frag (m89): col = lane&15, row = (lane>>4)*4 + r.
#pragma unroll
        for (int cf = 0; cf < 4; ++cf)
#pragma unroll
            for (int r = 0; r < 4; ++r)
                part[w][(lane >> 4) * 4 + r][cf * 16 + fr] = acc[cf][r];

        __syncthreads();

        float s0 = 0.f, s1 = 0.f;
#pragma unroll
        for (int p = 0; p < 8; ++p) {
            f32x2 v = *(const f32x2*)&part[p][orow][oc];
            s0 += v[0];
            s1 += v[1];
        }

        float o0 = tanhf(s0 + bv0 + xv[0]);
        float o1 = tanhf(s1 + bv1 + xv[1]);

        coh_store32(Nh + idx, pack_bf16(o0, o1));   // cross-block: coherent

        f32x2 ov; ov[0] = o0; ov[1] = o1;
        if (t + 1 < T_STEPS) {
            // ---- group barrier, fence-free ----
            asm volatile("s_waitcnt vmcnt(0)" ::: "memory");  // Nh at MALL
            __syncthreads();
            if (tid == 0) atomicAdd(&mycnt[t], 1u);           // device scope
            *(f32x2*)(io + idx) = ov;        // private store drifts into spin
            if (tid == 0)
                while (__hip_atomic_load(&mycnt[t], __ATOMIC_RELAXED,
                                         __HIP_MEMORY_SCOPE_AGENT) < (unsigned)GB)
                    __builtin_amdgcn_s_sleep(1);
            __syncthreads();
        } else {
            *(f32x2*)(io + idx) = ov;
        }

        xv = xn;
        __bf16* tmp = (__bf16*)Ah; Ah = Nh; Nh = tmp;
    }
}

// ---------------------------------------------------------------------------
// Fallback step (multi-launch) if ws_size is too small.
// ---------------------------------------------------------------------------
__global__ __launch_bounds__(256, 2)
void k_step_f32(const float* __restrict__ hprev, const float* __restrict__ Wh,
                const float* __restrict__ bias, float* __restrict__ io)
{
    __shared__ __align__(16) float part[4][32][32];

    const int tid  = threadIdx.x;
    const int lane = tid & 63;
    const int w    = tid >> 6;

    const int id  = blockIdx.x;
    const int j_  = id >> 3;
    const int bn  = ((id & 7) * 8 + (j_ >> 2)) * 32;
    const int bm  = (j_ & 3) * 32;

    const int fr = lane & 15;
    const int kq = (lane >> 4) * 8;

    const float* A0 = hprev + (size_t)(bm + fr)      * LAT;
    const float* A1 = hprev + (size_t)(bm + 16 + fr) * LAT;
    const float* B0 = Wh    + (size_t)(bn + fr)      * LAT;
    const float* B1 = Wh    + (size_t)(bn + 16 + fr) * LAT;

    f32x4 acc[2][2] = {};
    const int kbase = w * 512 + kq;
#pragma unroll
    for (int i = 0; i < 16; ++i) {
        const int k = kbase + i * 32;
        f32x4 a00 = *(const f32x4*)(A0 + k);
        f32x4 a01 = *(const f32x4*)(A0 + k + 4);
        f32x4 a10 = *(const f32x4*)(A1 + k);
        f32x4 a11 = *(const f32x4*)(A1 + k + 4);
        f32x4 b00 = *(const f32x4*)(B0 + k);
        f32x4 b01 = *(const f32x4*)(B0 + k + 4);
        f32x4 b10 = *(const f32x4*)(B1 + k);
        f32x4 b11 = *(const f32x4*)(B1 + k + 4);

        bf16x8 ah0, al0, ah1, al1, bh0, bl0, bh1, bl1;
        split8(a00, a01, ah0, al0);
        split8(a10, a11, ah1, al1);
        split8(b00, b01, bh0, bl0);
        split8(b10, b11, bh1, bl1);

        acc[0][0] = MFMA16(ah0, bh0, acc[0][0], 0, 0, 0);
        acc[0][1] = MFMA16(ah0, bh1, acc[0][1], 0, 0, 0);
        acc[1][0] = MFMA16(ah1, bh0, acc[1][0], 0, 0, 0);
        acc[1][1] = MFMA16(ah1, bh1, acc[1][1], 0, 0, 0);
        acc[0][0] = MFMA16(al0, bh0, acc[0][0], 0, 0, 0);
        acc[0][1] = MFMA16(al0, bh1, acc[0][1], 0, 0, 0);
        acc[1][0] = MFMA16(al1, bh0, acc[1][0], 0, 0, 0);
        acc[1][1] = MFMA16(al1, bh1, acc[1][1], 0, 0, 0);
        acc[0][0] = MFMA16(ah0, bl0, acc[0][0], 0, 0, 0);
        acc[0][1] = MFMA16(ah0, bl1, acc[0][1], 0, 0, 0);
        acc[1][0] = MFMA16(ah1, bl0, acc[1][0], 0, 0, 0);
        acc[1][1] = MFMA16(ah1, bl1, acc[1][1], 0, 0, 0);
    }

#pragma unroll
    for (int mi = 0; mi < 2; ++mi)
#pragma unroll
        for (int nj = 0; nj < 2; ++nj)
#pragma unroll
            for (int r = 0; r < 4; ++r)
                part[w][mi * 16 + (lane >> 4) * 4 + r][nj * 16 + fr] = acc[mi][nj][r];

    __syncthreads();

    const int row = tid >> 3;
    const int c   = (tid & 7) * 4;
    f32x4 s0 = *(const f32x4*)&part[0][row][c];
    f32x4 s1 = *(const f32x4*)&part[1][row][c];
    f32x4 s2 = *(const f32x4*)&part[2][row][c];
    f32x4 s3 = *(const f32x4*)&part[3][row][c];

    float* outp = io + (size_t)(bm + row) * LAT + bn + c;
    f32x4 xv = *(const f32x4*)outp;
    f32x4 bv = *(const f32x4*)(bias + bn + c);
    f32x4 o;
#pragma unroll
    for (int e = 0; e < 4; ++e)
        o[e] = tanhf(s0[e] + s1[e] + s2[e] + s3[e] + xv[e] + bv[e]);
    *(f32x4*)outp = o;
}

extern "C" void kernel_launch(void* const* d_in, const int* in_sizes, int n_in,
                              void* d_out, int out_size, void* d_ws, size_t ws_size,
                              hipStream_t stream) {
    const float* x  = (const float*)d_in[0];
    const float* Wi = (const float*)d_in[1];
    const float* bi = (const float*)d_in[2];
    const float* Wh = (const float*)d_in[3];
    const float* bh = (const float*)d_in[4];
    float* out = (float*)d_out;

    const size_t whbytes = (size_t)LAT * LAT * 2;    // 8 MB  (Wh hi plane)
    const size_t hbytes  = (size_t)BATCH * LAT * 2;  // 512 KB per h plane
    const size_t cbytes  = (size_t)NG * T_STEPS * sizeof(unsigned int);
    const size_t need    = whbytes + 2 * hbytes + cbytes;
    const bool fast = ws_size >= need;

    char* wsb = (char*)d_ws;
    __bf16* Whi = (__bf16*)wsb;
    __bf16* p0h = (__bf16*)(wsb + whbytes);
    __bf16* p1h = (__bf16*)(wsb + whbytes + hbytes);
    unsigned int* cnt = (unsigned int*)(wsb + whbytes + 2 * hbytes);

    if (fast) {
        hipMemsetAsync(cnt, 0, cbytes, stream);      // barrier counters
        k_prep<<<(LAT * LAT) / (256 * 4), 256, 0, stream>>>(Wh, Whi);
    }

    dim3 g1(LAT / 128, (T_STEPS * BATCH) / 128);     // (16, 256)
    k_xproj<<<g1, 256, 0, stream>>>(x, Wi, bi, out, fast ? p0h : nullptr);

    if (fast) {
        k_recur<<<NG * GB, 512, 0, stream>>>(Whi, p0h, p1h, bh, out, cnt);
    } else {
        for (int t = 1; t < T_STEPS; ++t)
            k_step_f32<<<256, 256, 0, stream>>>(out + (size_t)(t - 1) * BATCH * LAT,
                                                Wh, bh,
                                                out + (size_t)t * BATCH * LAT);
    }
}

// Round 9
// 1702.814 us; speedup vs baseline: 1.0469x; 1.0469x over previous
//
#include <hip/hip_runtime.h>
#include <hip/hip_bf16.h>
#include <math.h>

#define T_STEPS 256
#define BATCH   128
#define IN_DIM  1024
#define LAT     2048

// recurrence decomposition
#define NG      8     // independent batch-row groups (16 rows each)
#define GB      32    // blocks per group (64 cols each)
#define GROWS   16
#define GCOLS   64

typedef __bf16 bf16x8 __attribute__((ext_vector_type(8)));
typedef __bf16 bf16x4 __attribute__((ext_vector_type(4)));
typedef float  f32x4  __attribute__((ext_vector_type(4)));
typedef float  f32x2  __attribute__((ext_vector_type(2)));

#define MFMA16 __builtin_amdgcn_mfma_f32_16x16x32_bf16

// ---------------------------------------------------------------------------
// Coherent (agent-scope, L1/L2-bypassing, MALL-served) accessors.
// ---------------------------------------------------------------------------
__device__ __forceinline__ void coh_store32(__bf16* p, unsigned int v) {
    __hip_atomic_store((unsigned int*)p, v,
                       __ATOMIC_RELAXED, __HIP_MEMORY_SCOPE_AGENT);
}
__device__ __forceinline__ unsigned int pack_bf16(float a, float b) {
    union { __bf16 h[2]; unsigned int u; } p;
    p.h[0] = (__bf16)a; p.h[1] = (__bf16)b;
    return p.u;
}
__device__ __forceinline__ unsigned int coh_poll_u32(const unsigned int* p) {
    unsigned int v;
    asm volatile("global_load_dword %0, %1, off sc1" : "=v"(v) : "v"(p) : "memory");
    asm volatile("s_waitcnt vmcnt(0)" ::: "memory");
    return v;
}
__device__ __forceinline__ void coh_store_flag(unsigned int* p) {
    unsigned int one = 1;
    asm volatile("global_store_dword %0, %1, off sc1"
                 :: "v"(p), "v"(one) : "memory");
}

// ---------------------------------------------------------------------------
// LDS tile helpers for k_xproj (unchanged).
// ---------------------------------------------------------------------------
__device__ __forceinline__ int swz(int row, int kbyte) {
    return (row * 64 + kbyte) ^ ((row & 7) << 4);
}

template<int ROWS>
__device__ __forceinline__ void stage_load(const float* __restrict__ src, int ld,
                                           int tid, f32x4* regs) {
#pragma unroll
    for (int rnd = 0; rnd < ROWS / 32; ++rnd) {
        int r  = rnd * 32 + (tid >> 3);
        int kc = (tid & 7) * 4;
        regs[rnd] = *(const f32x4*)(src + (size_t)r * ld + kc);
    }
}

template<int ROWS>
__device__ __forceinline__ void stage_write(const f32x4* regs, char* hi, char* lo,
                                            int tid) {
#pragma unroll
    for (int rnd = 0; rnd < ROWS / 32; ++rnd) {
        int r  = rnd * 32 + (tid >> 3);
        int kc = (tid & 7) * 4;
        bf16x4 vh, vl;
        f32x4  v = regs[rnd];
#pragma unroll
        for (int e = 0; e < 4; ++e) {
            float x = v[e];
            __bf16 h = (__bf16)x;
            vh[e] = h;
            vl[e] = (__bf16)(x - (float)h);
        }
        int off = swz(r, kc * 2);
        *(bf16x4*)(hi + off) = vh;
        *(bf16x4*)(lo + off) = vl;
    }
}

__device__ __forceinline__ bf16x8 ld_frag(const char* p, int row, int kb) {
    return *(const bf16x8*)(p + swz(row, kb));
}

__device__ __forceinline__ void split8(f32x4 v0, f32x4 v1, bf16x8& hi, bf16x8& lo) {
#pragma unroll
    for (int e = 0; e < 4; ++e) {
        __bf16 h0 = (__bf16)v0[e];
        hi[e]     = h0;
        lo[e]     = (__bf16)(v0[e] - (float)h0);
        __bf16 h1 = (__bf16)v1[e];
        hi[e + 4] = h1;
        lo[e + 4] = (__bf16)(v1[e] - (float)h1);
    }
}

// ---------------------------------------------------------------------------
// Prep: Wh (fp32) -> hi bf16 plane.
// ---------------------------------------------------------------------------
__global__ __launch_bounds__(256)
void k_prep(const float* __restrict__ W, __bf16* __restrict__ hi)
{
    size_t i = ((size_t)blockIdx.x * 256 + threadIdx.x) * 4;
    f32x4 v = *(const f32x4*)(W + i);
    bf16x4 vh;
#pragma unroll
    for (int e = 0; e < 4; ++e) vh[e] = (__bf16)v[e];
    *(bf16x4*)(hi + i) = vh;
}

// ---------------------------------------------------------------------------
// Phase 1: xi = x @ W_i^T + b_i -> out (fp32); t==0 rows get tanh and seed
// the h ping buffer (bf16-hi).
// ---------------------------------------------------------------------------
__global__ __launch_bounds__(256, 2)
void k_xproj(const float* __restrict__ x, const float* __restrict__ Wi,
             const float* __restrict__ bi, float* __restrict__ out,
             __bf16* __restrict__ h0hi)
{
    __shared__ __align__(16) char lds[32 * 1024];
    char* Ahi = lds;
    char* Alo = lds + 8192;
    char* Bhi = lds + 16384;
    char* Blo = lds + 24576;

    int tid  = threadIdx.x;
    int lane = tid & 63;
    int w    = tid >> 6;
    int wm   = (w >> 1) * 64;
    int wn   = (w & 1) * 64;
    int bm   = blockIdx.y * 128;
    int bn   = blockIdx.x * 128;

    const float* Abase = x  + (size_t)bm * IN_DIM;
    const float* Bbase = Wi + (size_t)bn * IN_DIM;

    f32x4 acc[4][4] = {};
    f32x4 ra[4], rb[4];

    stage_load<128>(Abase, IN_DIM, tid, ra);
    stage_load<128>(Bbase, IN_DIM, tid, rb);

    for (int k0 = 0; k0 < IN_DIM; k0 += 32) {
        stage_write<128>(ra, Ahi, Alo, tid);
        stage_write<128>(rb, Bhi, Blo, tid);
        __syncthreads();

        if (k0 + 32 < IN_DIM) {
            stage_load<128>(Abase + k0 + 32, IN_DIM, tid, ra);
            stage_load<128>(Bbase + k0 + 32, IN_DIM, tid, rb);
        }

        int kb = (lane >> 4) * 16;
        bf16x8 ah[4], al[4], bh[4], bl[4];
#pragma unroll
        for (int i = 0; i < 4; ++i) {
            int rrow = i * 16 + (lane & 15);
            ah[i] = ld_frag(Ahi, wm + rrow, kb);
            al[i] = ld_frag(Alo, wm + rrow, kb);
            bh[i] = ld_frag(Bhi, wn + rrow, kb);
            bl[i] = ld_frag(Blo, wn + rrow, kb);
        }
#pragma unroll
        for (int i = 0; i < 4; ++i)
#pragma unroll
            for (int j = 0; j < 4; ++j) {
                acc[i][j] = MFMA16(ah[i], bh[j], acc[i][j], 0, 0, 0);
                acc[i][j] = MFMA16(ah[i], bl[j], acc[i][j], 0, 0, 0);
                acc[i][j] = MFMA16(al[i], bh[j], acc[i][j], 0, 0, 0);
            }
        __syncthreads();
    }

#pragma unroll
    for (int j = 0; j < 4; ++j) {
        int n = bn + wn + j * 16 + (lane & 15);
        float bias = bi[n];
#pragma unroll
        for (int i = 0; i < 4; ++i) {
            int m0 = bm + wm + i * 16 + ((lane >> 4) * 4);
#pragma unroll
            for (int r = 0; r < 4; ++r) {
                float v = acc[i][j][r] + bias;
                if (m0 + r < BATCH) {
                    v = tanhf(v);                       // t == 0: h0 = tanh(xi)
                    if (h0hi)
                        h0hi[(size_t)(m0 + r) * LAT + n] = (__bf16)v;
                }
                out[(size_t)(m0 + r) * LAT + n] = v;
            }
        }
    }
}

// coherent 16-B load, agent scope (sc1): bypasses L1/L2, served by MALL
#define LOADA(dst, off)                                                       \
    asm volatile("global_load_dwordx4 %0, %1, off offset:" #off " sc1"        \
                 : "=v"(dst) : "v"(Ar) : "memory")

// opaque asm load: result cannot be rematerialized -> forces register parking
#define LOADB(dst, base, off)                                                 \
    asm volatile("global_load_dwordx4 %0, %1, off offset:" #off               \
                 : "=v"(dst) : "v"(base))

// ---------------------------------------------------------------------------
// Phase 2 (v9): persistent, fence-free, B-parked (AGPR), split-phase flags.
// The group counter-barrier is replaced by per-(step, col-block) ready flags:
// producer block sets flag[t][rg][cb] once its Nh stores are vmcnt-drained;
// consumer WAVE w waits only on the 4 col-block flags covering its K-slice.
// Wave-union transitivity keeps ping-pong write-after-read safe: a block at
// step t+2 waited (across its 8 waves) on ALL flags[t+1], which implies every
// block in the group finished reading plane[t%2].
// ---------------------------------------------------------------------------
__global__ __launch_bounds__(512, 2)
void k_recur(const __bf16* __restrict__ Whi,
             __bf16* __restrict__ p0h, __bf16* __restrict__ p1h,
             const float* __restrict__ bias, float* __restrict__ out,
             unsigned int* __restrict__ flags)
{
    __shared__ __align__(16) float part[8][GROWS][GCOLS + 2];   // pad 64->66

    const int tid  = threadIdx.x;
    const int lane = tid & 63;
    const int w    = tid >> 6;              // wave id == K-slice (0..7)

    const int bid = blockIdx.x;
    const int rg  = bid >> 5;               // row group 0..7
    const int cb  = bid & 31;               // col block 0..31 (XCD = cb%8)
    const int bm  = rg * GROWS;
    const int bn  = cb * GCOLS;

    const int fr    = lane & 15;
    const int kq    = (lane >> 4) * 8;
    const int kbase = w * 256 + kq;

    // --- park this wave's Wh strip in registers via opaque asm loads ---
    bf16x8 bq[4][8];
    {
        const __bf16* B0 = Whi + (size_t)(bn + fr) * LAT + kbase;
        const __bf16* B1 = B0 + (size_t)16 * LAT;
        const __bf16* B2 = B0 + (size_t)32 * LAT;
        const __bf16* B3 = B0 + (size_t)48 * LAT;
        LOADB(bq[0][0], B0,   0); LOADB(bq[0][1], B0,  64);
        LOADB(bq[0][2], B0, 128); LOADB(bq[0][3], B0, 192);
        LOADB(bq[0][4], B0, 256); LOADB(bq[0][5], B0, 320);
        LOADB(bq[0][6], B0, 384); LOADB(bq[0][7], B0, 448);
        LOADB(bq[1][0], B1,   0); LOADB(bq[1][1], B1,  64);
        LOADB(bq[1][2], B1, 128); LOADB(bq[1][3], B1, 192);
        LOADB(bq[1][4], B1, 256); LOADB(bq[1][5], B1, 320);
        LOADB(bq[1][6], B1, 384); LOADB(bq[1][7], B1, 448);
        LOADB(bq[2][0], B2,   0); LOADB(bq[2][1], B2,  64);
        LOADB(bq[2][2], B2, 128); LOADB(bq[2][3], B2, 192);
        LOADB(bq[2][4], B2, 256); LOADB(bq[2][5], B2, 320);
        LOADB(bq[2][6], B2, 384); LOADB(bq[2][7], B2, 448);
        LOADB(bq[3][0], B3,   0); LOADB(bq[3][1], B3,  64);
        LOADB(bq[3][2], B3, 128); LOADB(bq[3][3], B3, 192);
        LOADB(bq[3][4], B3, 256); LOADB(bq[3][5], B3, 320);
        LOADB(bq[3][6], B3, 384); LOADB(bq[3][7], B3, 448);
        asm volatile("s_waitcnt vmcnt(0)" ::: "memory");
        __builtin_amdgcn_sched_barrier(0);
    }

    // combine-phase constants: 512 threads, each owns 2 consecutive cols.
    const int    orow = tid >> 5;                 // 0..15
    const int    oc   = (tid & 31) * 2;           // 0..62
    const size_t idx  = (size_t)(bm + orow) * LAT + bn + oc;
    const float  bv0  = bias[bn + oc];
    const float  bv1  = bias[bn + oc + 1];

    const __bf16* Ah = p0h;                 // read plane (h_{t-1})
    __bf16*       Nh = p1h;                 // write plane (h_t)

    // prologue: xi for t=1
    f32x2 xv = *(const f32x2*)(out + (size_t)1 * (BATCH * LAT) + idx);

    for (int t = 1; t < T_STEPS; ++t) {
        float* io = out + (size_t)t * (BATCH * LAT);

        // ---- wait (per wave) for the 4 producers of this K-slice ----
        if (t > 1) {
            const unsigned int* fp =
                flags + ((size_t)(t - 1) * NG + rg) * GB + w * 4;
            for (;;) {
                unsigned int f = 1;
                if (lane < 4) f = coh_poll_u32(fp + lane);
                if (__all(f != 0)) break;
                __builtin_amdgcn_s_sleep(2);
            }
        }

        const __bf16* Ar = Ah + (size_t)(bm + fr) * LAT + kbase;

        bf16x8 a[8];
        LOADA(a[0],   0);
        LOADA(a[1],  64);
        LOADA(a[2], 128);
        LOADA(a[3], 192);
        LOADA(a[4], 256);
        LOADA(a[5], 320);
        LOADA(a[6], 384);
        LOADA(a[7], 448);
        asm volatile("s_waitcnt vmcnt(0)" ::: "memory");
        __builtin_amdgcn_sched_barrier(0);

        f32x4 acc[4] = {};
#pragma unroll
        for (int i = 0; i < 8; ++i)
#pragma unroll
            for (int cf = 0; cf < 4; ++cf)
                acc[cf] = MFMA16(a[i], bq[cf][i], acc[cf], 0, 0, 0);

        // prefetch next step's xi (hidden under reduce)
        f32x2 xn = {};
        if (t + 1 < T_STEPS)
            xn = *(const f32x2*)(out + (size_t)(t + 1) * (BATCH * LAT) + idx);

        // dump partials. C-frag (m89): col = lane&15, row = (lane>>4)*4 + r.
#pragma unroll
        for (int cf = 0; cf < 4; ++cf)
#pragma unroll
            for (int r = 0; r < 4; ++r)
                part[w][(lane >> 4) * 4 + r][cf * 16 + fr] = acc[cf][r];

        __syncthreads();

        float s0 = 0.f, s1 = 0.f;
#pragma unroll
        for (int p = 0; p < 8; ++p) {
            f32x2 v = *(const f32x2*)&part[p][orow][oc];
            s0 += v[0];
            s1 += v[1];
        }

        float o0 = tanhf(s0 + bv0 + xv[0]);
        float o1 = tanhf(s1 + bv1 + xv[1]);

        coh_store32(Nh + idx, pack_bf16(o0, o1));   // cross-block data

        // drain Nh (per wave), then block-wide rendezvous, then publish flag
        asm volatile("s_waitcnt vmcnt(0)" ::: "memory");
        __syncthreads();
        if (tid == 0 && t + 1 < T_STEPS)
            coh_store_flag(flags + ((size_t)t * NG + rg) * GB + cb);

        // io store AFTER the flag publish: its HBM-ack latency drains during
        // the next poll window instead of delaying the producers' flag.
        f32x2 ov; ov[0] = o0; ov[1] = o1;
        *(f32x2*)(io + idx) = ov;

        xv = xn;
        __bf16* tmp = (__bf16*)Ah; Ah = Nh; Nh = tmp;
    }
}

// ---------------------------------------------------------------------------
// Fallback step (multi-launch) if ws_size is too small.
// ---------------------------------------------------------------------------
__global__ __launch_bounds__(256, 2)
void k_step_f32(const float* __restrict__ hprev, const float* __restrict__ Wh,
                const float* __restrict__ bias, float* __restrict__ io)
{
    __shared__ __align__(16) float part[4][32][32];

    const int tid  = threadIdx.x;
    const int lane = tid & 63;
    const int w    = tid >> 6;

    const int id  = blockIdx.x;
    const int j_  = id >> 3;
    const int bn  = ((id & 7) * 8 + (j_ >> 2)) * 32;
    const int bm  = (j_ & 3) * 32;

    const int fr = lane & 15;
    const int kq = (lane >> 4) * 8;

    const float* A0 = hprev + (size_t)(bm + fr)      * LAT;
    const float* A1 = hprev + (size_t)(bm + 16 + fr) * LAT;
    const float* B0 = Wh    + (size_t)(bn + fr)      * LAT;
    const float* B1 = Wh    + (size_t)(bn + 16 + fr) * LAT;

    f32x4 acc[2][2] = {};
    const int kbase = w * 512 + kq;
#pragma unroll
    for (int i = 0; i < 16; ++i) {
        const int k = kbase + i * 32;
        f32x4 a00 = *(const f32x4*)(A0 + k);
        f32x4 a01 = *(const f32x4*)(A0 + k + 4);
        f32x4 a10 = *(const f32x4*)(A1 + k);
        f32x4 a11 = *(const f32x4*)(A1 + k + 4);
        f32x4 b00 = *(const f32x4*)(B0 + k);
        f32x4 b01 = *(const f32x4*)(B0 + k + 4);
        f32x4 b10 = *(const f32x4*)(B1 + k);
        f32x4 b11 = *(const f32x4*)(B1 + k + 4);

        bf16x8 ah0, al0, ah1, al1, bh0, bl0, bh1, bl1;
        split8(a00, a01, ah0, al0);
        split8(a10, a11, ah1, al1);
        split8(b00, b01, bh0, bl0);
        split8(b10, b11, bh1, bl1);

        acc[0][0] = MFMA16(ah0, bh0, acc[0][0], 0, 0, 0);
        acc[0][1] = MFMA16(ah0, bh1, acc[0][1], 0, 0, 0);
        acc[1][0] = MFMA16(ah1, bh0, acc[1][0], 0, 0, 0);
        acc[1][1] = MFMA16(ah1, bh1, acc[1][1], 0, 0, 0);
        acc[0][0] = MFMA16(al0, bh0, acc[0][0], 0, 0, 0);
        acc[0][1] = MFMA16(al0, bh1, acc[0][1], 0, 0, 0);
        acc[1][0] = MFMA16(al1, bh0, acc[1][0], 0, 0, 0);
        acc[1][1] = MFMA16(al1, bh1, acc[1][1], 0, 0, 0);
        acc[0][0] = MFMA16(ah0, bl0, acc[0][0], 0, 0, 0);
        acc[0][1] = MFMA16(ah0, bl1, acc[0][1], 0, 0, 0);
        acc[1][0] = MFMA16(ah1, bl0, acc[1][0], 0, 0, 0);
        acc[1][1] = MFMA16(ah1, bl1, acc[1][1], 0, 0, 0);
    }

#pragma unroll
    for (int mi = 0; mi < 2; ++mi)
#pragma unroll
        for (int nj = 0; nj < 2; ++nj)
#pragma unroll
            for (int r = 0; r < 4; ++r)
                part[w][mi * 16 + (lane >> 4) * 4 + r][nj * 16 + fr] = acc[mi][nj][r];

    __syncthreads();

    const int row = tid >> 3;
    const int c   = (tid & 7) * 4;
    f32x4 s0 = *(const f32x4*)&part[0][row][c];
    f32x4 s1 = *(const f32x4*)&part[1][row][c];
    f32x4 s2 = *(const f32x4*)&part[2][row][c];
    f32x4 s3 = *(const f32x4*)&part[3][row][c];

    float* outp = io + (size_t)(bm + row) * LAT + bn + c;
    f32x4 xv = *(const f32x4*)outp;
    f32x4 bv = *(const f32x4*)(bias + bn + c);
    f32x4 o;
#pragma unroll
    for (int e = 0; e < 4; ++e)
        o[e] = tanhf(s0[e] + s1[e] + s2[e] + s3[e] + xv[e] + bv[e]);
    *(f32x4*)outp = o;
}

extern "C" void kernel_launch(void* const* d_in, const int* in_sizes, int n_in,
                              void* d_out, int out_size, void* d_ws, size_t ws_size,
                              hipStream_t stream) {
    const float* x  = (const float*)d_in[0];
    const float* Wi = (const float*)d_in[1];
    const float* bi = (const float*)d_in[2];
    const float* Wh = (const float*)d_in[3];
    const float* bh = (const float*)d_in[4];
    float* out = (float*)d_out;

    const size_t whbytes = (size_t)LAT * LAT * 2;    // 8 MB  (Wh hi plane)
    const size_t hbytes  = (size_t)BATCH * LAT * 2;  // 512 KB per h plane
    const size_t fbytes  = (size_t)T_STEPS * NG * GB * sizeof(unsigned int);
    const size_t need    = whbytes + 2 * hbytes + fbytes;
    const bool fast = ws_size >= need;

    char* wsb = (char*)d_ws;
    __bf16* Whi = (__bf16*)wsb;
    __bf16* p0h = (__bf16*)(wsb + whbytes);
    __bf16* p1h = (__bf16*)(wsb + whbytes + hbytes);
    unsigned int* flags = (unsigned int*)(wsb + whbytes + 2 * hbytes);

    if (fast) {
        hipMemsetAsync(flags, 0, fbytes, stream);    // ready flags
        k_prep<<<(LAT * LAT) / (256 * 4), 256, 0, stream>>>(Wh, Whi);
    }

    dim3 g1(LAT / 128, (T_STEPS * BATCH) / 128);     // (16, 256)
    k_xproj<<<g1, 256, 0, stream>>>(x, Wi, bi, out, fast ? p0h : nullptr);

    if (fast) {
        k_recur<<<NG * GB, 512, 0, stream>>>(Whi, p0h, p1h, bh, out, flags);
    } else {
        for (int t = 1; t < T_STEPS; ++t)
            k_step_f32<<<256, 256, 0, stream>>>(out + (size_t)(t - 1) * BATCH * LAT,
                                                Wh, bh,
                                                out + (size_t)t * BATCH * LAT);
    }
}

// Round 12
// 1419.731 us; speedup vs baseline: 1.2557x; 1.1994x over previous
//
#include <hip/hip_runtime.h>
#include <hip/hip_bf16.h>
#include <math.h>

#define T_STEPS 256
#define BATCH   128
#define IN_DIM  1024
#define LAT     2048
#define NBLK    256

// recurrence decomposition: group rg = XCD-congruence class (bid & 7)
#define NG      8     // independent batch-row groups (16 rows each)
#define GB      32    // blocks per group (64 cols each)
#define GROWS   16
#define GCOLS   64

typedef __bf16 bf16x8 __attribute__((ext_vector_type(8)));
typedef __bf16 bf16x4 __attribute__((ext_vector_type(4)));
typedef float  f32x4  __attribute__((ext_vector_type(4)));
typedef float  f32x2  __attribute__((ext_vector_type(2)));

#define MFMA16 __builtin_amdgcn_mfma_f32_16x16x32_bf16

// ---------------------------------------------------------------------------
// MALL-coherent accessors (sc1 = bypass L1+L2, meet at the MALL). These are
// the ONLY cross-block ordering primitives — proven in rounds 6-9.
// ---------------------------------------------------------------------------
__device__ __forceinline__ unsigned int poll_sc1(const unsigned int* p) {
    unsigned int v;
    asm volatile("global_load_dword %0, %1, off sc1" : "=v"(v) : "v"(p) : "memory");
    asm volatile("s_waitcnt vmcnt(0)" ::: "memory");
    return v;
}
__device__ __forceinline__ void st_sc1(unsigned int* p, unsigned int v) {
    asm volatile("global_store_dword %0, %1, off sc1" :: "v"(p), "v"(v) : "memory");
}
__device__ __forceinline__ unsigned int pack_bf16(float a, float b) {
    union { __bf16 h[2]; unsigned int u; } p;
    p.h[0] = (__bf16)a; p.h[1] = (__bf16)b;
    return p.u;
}

// ---------------------------------------------------------------------------
// LDS tile helpers for k_xproj (unchanged since round 3).
// ---------------------------------------------------------------------------
__device__ __forceinline__ int swz(int row, int kbyte) {
    return (row * 64 + kbyte) ^ ((row & 7) << 4);
}

template<int ROWS>
__device__ __forceinline__ void stage_load(const float* __restrict__ src, int ld,
                                           int tid, f32x4* regs) {
#pragma unroll
    for (int rnd = 0; rnd < ROWS / 32; ++rnd) {
        int r  = rnd * 32 + (tid >> 3);
        int kc = (tid & 7) * 4;
        regs[rnd] = *(const f32x4*)(src + (size_t)r * ld + kc);
    }
}

template<int ROWS>
__device__ __forceinline__ void stage_write(const f32x4* regs, char* hi, char* lo,
                                            int tid) {
#pragma unroll
    for (int rnd = 0; rnd < ROWS / 32; ++rnd) {
        int r  = rnd * 32 + (tid >> 3);
        int kc = (tid & 7) * 4;
        bf16x4 vh, vl;
        f32x4  v = regs[rnd];
#pragma unroll
        for (int e = 0; e < 4; ++e) {
            float x = v[e];
            __bf16 h = (__bf16)x;
            vh[e] = h;
            vl[e] = (__bf16)(x - (float)h);
        }
        int off = swz(r, kc * 2);
        *(bf16x4*)(hi + off) = vh;
        *(bf16x4*)(lo + off) = vl;
    }
}

__device__ __forceinline__ bf16x8 ld_frag(const char* p, int row, int kb) {
    return *(const bf16x8*)(p + swz(row, kb));
}

__device__ __forceinline__ void split8(f32x4 v0, f32x4 v1, bf16x8& hi, bf16x8& lo) {
#pragma unroll
    for (int e = 0; e < 4; ++e) {
        __bf16 h0 = (__bf16)v0[e];
        hi[e]     = h0;
        lo[e]     = (__bf16)(v0[e] - (float)h0);
        __bf16 h1 = (__bf16)v1[e];
        hi[e + 4] = h1;
        lo[e + 4] = (__bf16)(v1[e] - (float)h1);
    }
}

// ---------------------------------------------------------------------------
// Prep: Wh (fp32) -> hi bf16 plane.
// ---------------------------------------------------------------------------
__global__ __launch_bounds__(256)
void k_prep(const float* __restrict__ W, __bf16* __restrict__ hi)
{
    size_t i = ((size_t)blockIdx.x * 256 + threadIdx.x) * 4;
    f32x4 v = *(const f32x4*)(W + i);
    bf16x4 vh;
#pragma unroll
    for (int e = 0; e < 4; ++e) vh[e] = (__bf16)v[e];
    *(bf16x4*)(hi + i) = vh;
}

// ---------------------------------------------------------------------------
// Phase 1: xi = x @ W_i^T + b_i -> out (fp32); t==0 rows get tanh and seed
// h plane 0 (bf16).
// ---------------------------------------------------------------------------
__global__ __launch_bounds__(256, 2)
void k_xproj(const float* __restrict__ x, const float* __restrict__ Wi,
             const float* __restrict__ bi, float* __restrict__ out,
             __bf16* __restrict__ h0hi)
{
    __shared__ __align__(16) char lds[32 * 1024];
    char* Ahi = lds;
    char* Alo = lds + 8192;
    char* Bhi = lds + 16384;
    char* Blo = lds + 24576;

    int tid  = threadIdx.x;
    int lane = tid & 63;
    int w    = tid >> 6;
    int wm   = (w >> 1) * 64;
    int wn   = (w & 1) * 64;
    int bm   = blockIdx.y * 128;
    int bn   = blockIdx.x * 128;

    const float* Abase = x  + (size_t)bm * IN_DIM;
    const float* Bbase = Wi + (size_t)bn * IN_DIM;

    f32x4 acc[4][4] = {};
    f32x4 ra[4], rb[4];

    stage_load<128>(Abase, IN_DIM, tid, ra);
    stage_load<128>(Bbase, IN_DIM, tid, rb);

    for (int k0 = 0; k0 < IN_DIM; k0 += 32) {
        stage_write<128>(ra, Ahi, Alo, tid);
        stage_write<128>(rb, Bhi, Blo, tid);
        __syncthreads();

        if (k0 + 32 < IN_DIM) {
            stage_load<128>(Abase + k0 + 32, IN_DIM, tid, ra);
            stage_load<128>(Bbase + k0 + 32, IN_DIM, tid, rb);
        }

        int kb = (lane >> 4) * 16;
        bf16x8 ah[4], al[4], bh[4], bl[4];
#pragma unroll
        for (int i = 0; i < 4; ++i) {
            int rrow = i * 16 + (lane & 15);
            ah[i] = ld_frag(Ahi, wm + rrow, kb);
            al[i] = ld_frag(Alo, wm + rrow, kb);
            bh[i] = ld_frag(Bhi, wn + rrow, kb);
            bl[i] = ld_frag(Blo, wn + rrow, kb);
        }
#pragma unroll
        for (int i = 0; i < 4; ++i)
#pragma unroll
            for (int j = 0; j < 4; ++j) {
                acc[i][j] = MFMA16(ah[i], bh[j], acc[i][j], 0, 0, 0);
                acc[i][j] = MFMA16(ah[i], bl[j], acc[i][j], 0, 0, 0);
                acc[i][j] = MFMA16(al[i], bh[j], acc[i][j], 0, 0, 0);
            }
        __syncthreads();
    }

#pragma unroll
    for (int j = 0; j < 4; ++j) {
        int n = bn + wn + j * 16 + (lane & 15);
        float bias = bi[n];
#pragma unroll
        for (int i = 0; i < 4; ++i) {
            int m0 = bm + wm + i * 16 + ((lane >> 4) * 4);
#pragma unroll
            for (int r = 0; r < 4; ++r) {
                float v = acc[i][j][r] + bias;
                if (m0 + r < BATCH) {
                    v = tanhf(v);                       // t == 0: h0 = tanh(xi)
                    if (h0hi)
                        h0hi[(size_t)(m0 + r) * LAT + n] = (__bf16)v;
                }
                out[(size_t)(m0 + r) * LAT + n] = v;
            }
        }
    }
}

// A-fragment loads, sc1 (MALL) — ping-pong fallback path
#define LOADA_S(dst, base, off)                                               \
    asm volatile("global_load_dwordx4 %0, %1, off offset:" #off " sc1"        \
                 : "=v"(dst) : "v"(base) : "memory")

// opaque asm load: result cannot be rematerialized -> forces register parking
#define LOADB(dst, base, off)                                                 \
    asm volatile("global_load_dwordx4 %0, %1, off offset:" #off               \
                 : "=v"(dst) : "v"(base))

// ---------------------------------------------------------------------------
// Phase 2 (v12): persistent, fence-free, B-parked, split-phase flags.
// Two variants of the h exchange, same control flow as round 9 (proven):
//  FRESH=true : h_t -> its OWN plane (write-once-per-dispatch). Stores sc1
//    (drained before the sc1 flag, so flag-visible => data at MALL). Reads
//    are PLAIN CACHED loads: no stale L2 copy can exist (line written once,
//    read only after its flag; dispatch-boundary invalidation covers graph
//    replays). First reader fills the XCD L2; with rg=bid&7 the other 31
//    blocks of the group (which read the SAME 64KB) hit L2.
//  FRESH=false: round-9 ping-pong, sc1 loads (exact known-good fallback).
// ---------------------------------------------------------------------------
template<bool FRESH>
__device__ __forceinline__ void recur_body(
    const __bf16* __restrict__ Whi, __bf16* __restrict__ hpl,
    const float* __restrict__ bias, float* __restrict__ out,
    unsigned int* __restrict__ flags,
    float (&part)[8][GROWS][GCOLS + 2],
    int tid, int lane, int w, int rg, int cb, int bm, int bn)
{
    const int fr    = lane & 15;
    const int kq    = (lane >> 4) * 8;
    const int kbase = w * 256 + kq;
    const size_t HN = (size_t)BATCH * LAT;

    // --- park this wave's Wh strip in registers via opaque asm loads ---
    bf16x8 bq[4][8];
    {
        const __bf16* B0 = Whi + (size_t)(bn + fr) * LAT + kbase;
        const __bf16* B1 = B0 + (size_t)16 * LAT;
        const __bf16* B2 = B0 + (size_t)32 * LAT;
        const __bf16* B3 = B0 + (size_t)48 * LAT;
        LOADB(bq[0][0], B0,   0); LOADB(bq[0][1], B0,  64);
        LOADB(bq[0][2], B0, 128); LOADB(bq[0][3], B0, 192);
        LOADB(bq[0][4], B0, 256); LOADB(bq[0][5], B0, 320);
        LOADB(bq[0][6], B0, 384); LOADB(bq[0][7], B0, 448);
        LOADB(bq[1][0], B1,   0); LOADB(bq[1][1], B1,  64);
        LOADB(bq[1][2], B1, 128); LOADB(bq[1][3], B1, 192);
        LOADB(bq[1][4], B1, 256); LOADB(bq[1][5], B1, 320);
        LOADB(bq[1][6], B1, 384); LOADB(bq[1][7], B1, 448);
        LOADB(bq[2][0], B2,   0); LOADB(bq[2][1], B2,  64);
        LOADB(bq[2][2], B2, 128); LOADB(bq[2][3], B2, 192);
        LOADB(bq[2][4], B2, 256); LOADB(bq[2][5], B2, 320);
        LOADB(bq[2][6], B2, 384); LOADB(bq[2][7], B2, 448);
        LOADB(bq[3][0], B3,   0); LOADB(bq[3][1], B3,  64);
        LOADB(bq[3][2], B3, 128); LOADB(bq[3][3], B3, 192);
        LOADB(bq[3][4], B3, 256); LOADB(bq[3][5], B3, 320);
        LOADB(bq[3][6], B3, 384); LOADB(bq[3][7], B3, 448);
        asm volatile("s_waitcnt vmcnt(0)" ::: "memory");
        __builtin_amdgcn_sched_barrier(0);
    }

    // combine-phase constants: 512 threads, each owns 2 consecutive cols.
    const int    orow = tid >> 5;                 // 0..15
    const int    oc   = (tid & 31) * 2;           // 0..62
    const size_t idx  = (size_t)(bm + orow) * LAT + bn + oc;
    const float  bv0  = bias[bn + oc];
    const float  bv1  = bias[bn + oc + 1];

    // prologue: xi for t=1
    f32x2 xv = *(const f32x2*)(out + (size_t)1 * (BATCH * LAT) + idx);

    for (int t = 1; t < T_STEPS; ++t) {
        float* io = out + (size_t)t * (BATCH * LAT);

        // ---- wait (per wave) for the 4 producers of this K-slice ----
        if (t > 1) {
            const unsigned int* fp =
                flags + ((size_t)(t - 1) * NG + rg) * GB + w * 4;
            for (;;) {
                unsigned int f = 1;
                if (lane < 4) f = poll_sc1(fp + lane);
                if (__all(f != 0)) break;
                __builtin_amdgcn_s_sleep(1);
            }
        }

        const __bf16* Aplane = FRESH ? hpl + HN * (size_t)(t - 1)
                                     : hpl + HN * (size_t)((t - 1) & 1);
        const __bf16* Ar = Aplane + (size_t)(bm + fr) * LAT + kbase;

        bf16x8 a[8];
        if constexpr (FRESH) {
            // plain cached loads: line is write-once-per-dispatch, so no
            // stale-L2 hazard; 31 of 32 group blocks hit the XCD L2.
#pragma unroll
            for (int i = 0; i < 8; ++i)
                a[i] = *(const bf16x8*)(Ar + i * 32);
        } else {
            LOADA_S(a[0], Ar,   0); LOADA_S(a[1], Ar,  64);
            LOADA_S(a[2], Ar, 128); LOADA_S(a[3], Ar, 192);
            LOADA_S(a[4], Ar, 256); LOADA_S(a[5], Ar, 320);
            LOADA_S(a[6], Ar, 384); LOADA_S(a[7], Ar, 448);
            asm volatile("s_waitcnt vmcnt(0)" ::: "memory");
            __builtin_amdgcn_sched_barrier(0);
        }

        f32x4 acc[4] = {};
#pragma unroll
        for (int i = 0; i < 8; ++i)
#pragma unroll
            for (int cf = 0; cf < 4; ++cf)
                acc[cf] = MFMA16(a[i], bq[cf][i], acc[cf], 0, 0, 0);

        // prefetch next step's xi (hidden under reduce)
        f32x2 xn = {};
        if (t + 1 < T_STEPS)
            xn = *(const f32x2*)(out + (size_t)(t + 1) * (BATCH * LAT) + idx);

        // dump partials. C-frag (m89): col = lane&15, row = (lane>>4)*4 + r.
#pragma unroll
        for (int cf = 0; cf < 4; ++cf)
#pragma unroll
            for (int r = 0; r < 4; ++r)
                part[w][(lane >> 4) * 4 + r][cf * 16 + fr] = acc[cf][r];

        __syncthreads();

        float s0 = 0.f, s1 = 0.f;
#pragma unroll
        for (int p = 0; p < 8; ++p) {
            f32x2 v = *(const f32x2*)&part[p][orow][oc];
            s0 += v[0];
            s1 += v[1];
        }

        float o0 = tanhf(s0 + bv0 + xv[0]);
        float o1 = tanhf(s1 + bv1 + xv[1]);

        __bf16* Np = FRESH ? hpl + HN * (size_t)t
                           : hpl + HN * (size_t)(t & 1);
        st_sc1((unsigned int*)(Np + idx), pack_bf16(o0, o1));   // data, sc1

        // drain Nh, block-wide rendezvous, publish flag (sc1, proven order)
        asm volatile("s_waitcnt vmcnt(0)" ::: "memory");
        __syncthreads();
        if (tid == 0 && t + 1 < T_STEPS)
            st_sc1(flags + ((size_t)t * NG + rg) * GB + cb, 1u);

        // io store AFTER the flag publish (off the producer critical path)
        f32x2 ov; ov[0] = o0; ov[1] = o1;
        *(f32x2*)(io + idx) = ov;

        xv = xn;
    }
}

template<bool FRESH>
__global__ __launch_bounds__(512, 2)
void k_recur(const __bf16* __restrict__ Whi, __bf16* __restrict__ hpl,
             const float* __restrict__ bias, float* __restrict__ out,
             unsigned int* __restrict__ flags)
{
    __shared__ __align__(16) float part[8][GROWS][GCOLS + 2];

    const int tid  = threadIdx.x;
    const int lane = tid & 63;
    const int w    = tid >> 6;              // wave id == K-slice (0..7)

    const int bid = blockIdx.x;
    const int rg  = bid & 7;                // group = XCD-congruence class
    const int cb  = bid >> 3;               // col block 0..31
    const int bm  = rg * GROWS;
    const int bn  = cb * GCOLS;

    recur_body<FRESH>(Whi, hpl, bias, out, flags, part,
                      tid, lane, w, rg, cb, bm, bn);
}

// ---------------------------------------------------------------------------
// Fallback step (multi-launch) if ws_size is too small for any plane tier.
// ---------------------------------------------------------------------------
__global__ __launch_bounds__(256, 2)
void k_step_f32(const float* __restrict__ hprev, const float* __restrict__ Wh,
                const float* __restrict__ bias, float* __restrict__ io)
{
    __shared__ __align__(16) float part[4][32][32];

    const int tid  = threadIdx.x;
    const int lane = tid & 63;
    const int w    = tid >> 6;

    const int id  = blockIdx.x;
    const int j_  = id >> 3;
    const int bn  = ((id & 7) * 8 + (j_ >> 2)) * 32;
    const int bm  = (j_ & 3) * 32;

    const int fr = lane & 15;
    const int kq = (lane >> 4) * 8;

    const float* A0 = hprev + (size_t)(bm + fr)      * LAT;
    const float* A1 = hprev + (size_t)(bm + 16 + fr) * LAT;
    const float* B0 = Wh    + (size_t)(bn + fr)      * LAT;
    const float* B1 = Wh    + (size_t)(bn + 16 + fr) * LAT;

    f32x4 acc[2][2] = {};
    const int kbase = w * 512 + kq;
#pragma unroll
    for (int i = 0; i < 16; ++i) {
        const int k = kbase + i * 32;
        f32x4 a00 = *(const f32x4*)(A0 + k);
        f32x4 a01 = *(const f32x4*)(A0 + k + 4);
        f32x4 a10 = *(const f32x4*)(A1 + k);
        f32x4 a11 = *(const f32x4*)(A1 + k + 4);
        f32x4 b00 = *(const f32x4*)(B0 + k);
        f32x4 b01 = *(const f32x4*)(B0 + k + 4);
        f32x4 b10 = *(const f32x4*)(B1 + k);
        f32x4 b11 = *(const f32x4*)(B1 + k + 4);

        bf16x8 ah0, al0, ah1, al1, bh0, bl0, bh1, bl1;
        split8(a00, a01, ah0, al0);
        split8(a10, a11, ah1, al1);
        split8(b00, b01, bh0, bl0);
        split8(b10, b11, bh1, bl1);

        acc[0][0] = MFMA16(ah0, bh0, acc[0][0], 0, 0, 0);
        acc[0][1] = MFMA16(ah0, bh1, acc[0][1], 0, 0, 0);
        acc[1][0] = MFMA16(ah1, bh0, acc[1][0], 0, 0, 0);
        acc[1][1] = MFMA16(ah1, bh1, acc[1][1], 0, 0, 0);
        acc[0][0] = MFMA16(al0, bh0, acc[0][0], 0, 0, 0);
        acc[0][1] = MFMA16(al0, bh1, acc[0][1], 0, 0, 0);
        acc[1][0] = MFMA16(al1, bh0, acc[1][0], 0, 0, 0);
        acc[1][1] = MFMA16(al1, bh1, acc[1][1], 0, 0, 0);
        acc[0][0] = MFMA16(ah0, bl0, acc[0][0], 0, 0, 0);
        acc[0][1] = MFMA16(ah0, bl1, acc[0][1], 0, 0, 0);
        acc[1][0] = MFMA16(ah1, bl0, acc[1][0], 0, 0, 0);
        acc[1][1] = MFMA16(ah1, bl1, acc[1][1], 0, 0, 0);
    }

#pragma unroll
    for (int mi = 0; mi < 2; ++mi)
#pragma unroll
        for (int nj = 0; nj < 2; ++nj)
#pragma unroll
            for (int r = 0; r < 4; ++r)
                part[w][mi * 16 + (lane >> 4) * 4 + r][nj * 16 + fr] = acc[mi][nj][r];

    __syncthreads();

    const int row = tid >> 3;
    const int c   = (tid & 7) * 4;
    f32x4 s0 = *(const f32x4*)&part[0][row][c];
    f32x4 s1 = *(const f32x4*)&part[1][row][c];
    f32x4 s2 = *(const f32x4*)&part[2][row][c];
    f32x4 s3 = *(const f32x4*)&part[3][row][c];

    float* outp = io + (size_t)(bm + row) * LAT + bn + c;
    f32x4 xv = *(const f32x4*)outp;
    f32x4 bv = *(const f32x4*)(bias + bn + c);
    f32x4 o;
#pragma unroll
    for (int e = 0; e < 4; ++e)
        o[e] = tanhf(s0[e] + s1[e] + s2[e] + s3[e] + xv[e] + bv[e]);
    *(f32x4*)outp = o;
}

extern "C" void kernel_launch(void* const* d_in, const int* in_sizes, int n_in,
                              void* d_out, int out_size, void* d_ws, size_t ws_size,
                              hipStream_t stream) {
    const float* x  = (const float*)d_in[0];
    const float* Wi = (const float*)d_in[1];
    const float* bi = (const float*)d_in[2];
    const float* Wh = (const float*)d_in[3];
    const float* bh = (const float*)d_in[4];
    float* out = (float*)d_out;

    const size_t whbytes = (size_t)LAT * LAT * 2;    // 8 MB  (Wh hi plane)
    const size_t hbytes  = (size_t)BATCH * LAT * 2;  // 512 KB per h plane
    const size_t fbytes  = (size_t)T_STEPS * NG * GB * sizeof(unsigned int);

    const size_t need_fresh = whbytes + (size_t)T_STEPS * hbytes + fbytes; // ~136.5 MB
    const size_t need_pp    = whbytes + 2 * hbytes + fbytes;               // ~17.3 MB

    const bool fresh = ws_size >= need_fresh;
    const bool pp    = !fresh && ws_size >= need_pp;

    char* wsb = (char*)d_ws;
    __bf16* Whi = (__bf16*)wsb;
    __bf16* hpl = (__bf16*)(wsb + whbytes);
    const size_t nplanes = fresh ? T_STEPS : 2;
    unsigned int* flags = (unsigned int*)(wsb + whbytes + nplanes * hbytes);

    if (fresh || pp) {
        hipMemsetAsync(flags, 0, fbytes, stream);    // ready flags
        k_prep<<<(LAT * LAT) / (256 * 4), 256, 0, stream>>>(Wh, Whi);
    }

    dim3 g1(LAT / 128, (T_STEPS * BATCH) / 128);     // (16, 256)
    k_xproj<<<g1, 256, 0, stream>>>(x, Wi, bi, out,
                                    (fresh || pp) ? hpl : nullptr);

    if (fresh) {
        k_recur<true ><<<NBLK, 512, 0, stream>>>(Whi, hpl, bh, out, flags);
    } else if (pp) {
        k_recur<false><<<NBLK, 512, 0, stream>>>(Whi, hpl, bh, out, flags);
    } else {
        for (int t = 1; t < T_STEPS; ++t)
            k_step_f32<<<256, 256, 0, stream>>>(out + (size_t)(t - 1) * BATCH * LAT,
                                                Wh, bh,
                                                out + (size_t)t * BATCH * LAT);
    }
}